// Round 12
// baseline (114.635 us; speedup 1.0000x reference)
//
#include <hip/hip_runtime.h>

#define N_NODES 100000
#define N_EDGES 1600000
#define D_FEAT 32

#define BSH 7                 // bucket = dst >> 7  (128 nodes per bucket)
#define BMASK 127
#define NB 782                // ceil(100000/128)
#define CAPB 2432             // per-bucket capacity (mean 2046, ~8.5 sigma pad)

#define P1_BS 1024            // 4 edges/thread (1 int4 pair)
#define P1_TILE 4096
#define P1_CAP 16             // staging per bucket per block (mean ~5.2)

// ws layout (4-byte words):
//   cursorA [1024]        int    per-bucket fill cursors (init to b*CAPB)
//   pairs   [NB*CAPB]     int    packed (src<<7)|(dst&127), bucket-grouped
//   sfeat   [N_NODES*16]  uint   bf16-packed feat*dinv (2 feats per uint)
//
// Lessons carried: LDS f32 atomics lower to a slow non-DS path (R3/R5);
// scattered global atomics ~34ns (R5); deterministic cell placement loses
// to cursor atomics (R7); cooperative launch silently no-ops here (R8);
// bucket cost is not per-block fixed (R9) nor DS-duplication (R11).
// R12 single-variable: degree-ranked gather assignment (kills the
// max-of-16-Poisson wave divergence in the gather phase).

typedef float v4f __attribute__((ext_vector_type(4)));   // native vec for nontemporal builtins

static __device__ __forceinline__ unsigned pack_bf16(float a, float b) {
    unsigned ua = __float_as_uint(a);
    unsigned ub = __float_as_uint(b);
    ua = (ua + 0x7FFFu + ((ua >> 16) & 1u)) >> 16;   // RNE
    ub = (ub + 0x7FFFu + ((ub >> 16) & 1u)) >> 16;
    return (ua & 0xFFFFu) | (ub << 16);
}

__global__ void init_kernel(int* __restrict__ cursorA) {
    int b = blockIdx.x * blockDim.x + threadIdx.x;
    if (b < NB) cursorA[b] = b * CAPB;
}

// Pass 1: bucket edges by dst>>7 with LDS staging -> coalesced runs into
// fixed per-bucket regions. Slot-parallel drain. (Exact R6 config.)
__global__ void __launch_bounds__(P1_BS)
bucket_kernel(const int* __restrict__ edge_src,
              const int* __restrict__ edge_dst,
              int* __restrict__ cursorA,
              int* __restrict__ pairs, int n_edges) {
    __shared__ int s_cnt[NB];
    __shared__ int s_base[NB];
    __shared__ int s_buf[NB * P1_CAP];   // 782*16*4 = 50 KB

    int tile = blockIdx.x * P1_TILE;
    if (tile >= n_edges) return;

    for (int b = threadIdx.x; b < NB; b += P1_BS) s_cnt[b] = 0;
    __syncthreads();

    const int4* src4 = reinterpret_cast<const int4*>(edge_src);
    const int4* dst4 = reinterpret_cast<const int4*>(edge_dst);
    int tileq = blockIdx.x * (P1_TILE / 4);
    {
        int iq = tileq + threadIdx.x;            // 1024 int4s == 4096 edges
        if (iq * 4 < n_edges) {
            int4 sv = src4[iq];
            int4 dv = dst4[iq];
            int ss[4] = {sv.x, sv.y, sv.z, sv.w};
            int dd[4] = {dv.x, dv.y, dv.z, dv.w};
            #pragma unroll
            for (int u = 0; u < 4; ++u) {
                int b = dd[u] >> BSH;
                int packed = (ss[u] << BSH) | (dd[u] & BMASK);
                int p = atomicAdd(&s_cnt[b], 1);
                if (p < P1_CAP) {
                    s_buf[b * P1_CAP + p] = packed;
                } else {
                    int gp = atomicAdd(&cursorA[b], 1);   // rare overflow
                    pairs[gp] = packed;
                }
            }
        }
    }
    __syncthreads();

    for (int b = threadIdx.x; b < NB; b += P1_BS) {
        int c = min(s_cnt[b], P1_CAP);
        s_cnt[b] = c;
        s_base[b] = atomicAdd(&cursorA[b], c);
    }
    __syncthreads();

    // slot-parallel drain: 12512 slots / 1024 threads = 13 rounds
    for (int idx = threadIdx.x; idx < NB * P1_CAP; idx += P1_BS) {
        int b = idx >> 4;                 // P1_CAP == 16
        int slot = idx & (P1_CAP - 1);
        if (slot < s_cnt[b])
            pairs[s_base[b] + slot] = s_buf[idx];
    }
}

// Pass 2: one WG per bucket — degree histogram + bf16 sfeat rows.
__global__ void __launch_bounds__(512)
prep_kernel(const int* __restrict__ pairs,
            const int* __restrict__ cursorA,
            const float* __restrict__ feat,
            unsigned* __restrict__ sfeat) {
    __shared__ int h[128];
    __shared__ float dv_s[128];

    int b = blockIdx.x;
    int t = threadIdx.x;
    int base = b * CAPB;
    int cnt = min(cursorA[b] - base, CAPB);

    if (t < 128) h[t] = 0;
    __syncthreads();
    for (int i = t; i < cnt; i += 512)
        atomicAdd(&h[pairs[base + i] & BMASK], 1);
    __syncthreads();

    if (t < 128)
        dv_s[t] = rsqrtf(fmaxf((float)h[t], 1.0f));
    __syncthreads();

    // bf16 sfeat rows: sfeat[n] = bf16(feat[n] * dinv[n]), uint4 per 8 feats
    const float4* feat4 = reinterpret_cast<const float4*>(feat);
    uint4* sf4 = reinterpret_cast<uint4*>(sfeat);
    for (int idx = t; idx < 128 * 4; idx += 512) {
        int nl = idx >> 2;
        int q = idx & 3;
        int node = (b << BSH) + nl;
        if (node >= N_NODES) continue;
        float dvv = dv_s[nl];
        float4 fa = feat4[node * 8 + 2 * q];
        float4 fb = feat4[node * 8 + 2 * q + 1];
        uint4 pk;
        pk.x = pack_bf16(fa.x * dvv, fa.y * dvv);
        pk.y = pack_bf16(fa.z * dvv, fa.w * dvv);
        pk.z = pack_bf16(fb.x * dvv, fb.y * dvv);
        pk.w = pack_bf16(fb.z * dvv, fb.w * dvv);
        sf4[node * 4 + q] = pk;
    }
}

// Pass 3: one WG (512 threads) per bucket — fused counting sort (LDS only)
// + degree-ranked gather + Bernstein epilogue. Gather threads process
// nodes in degree-rank order so each wave's 16 nodes have ~equal trip
// counts (kills max-of-Poisson divergence).
__global__ void __launch_bounds__(512)
sortgather_kernel(const int* __restrict__ pairs,
                  const int* __restrict__ cursorA,
                  const float* __restrict__ feat,
                  const unsigned* __restrict__ sfeat,
                  float* __restrict__ out) {
    __shared__ int buf[CAPB];     // 9.5 KB
    __shared__ int outb[CAPB];    // 9.5 KB  (dst-sorted srcs)
    __shared__ int h[128];
    __shared__ int sc[128];
    __shared__ int cur[128];
    __shared__ float dv_s[128];
    __shared__ int dh[64];        // degree histogram (clamped to 63)
    __shared__ int perm[128];     // degree-rank -> node-local index

    int b = blockIdx.x;
    int t = threadIdx.x;
    int base = b * CAPB;
    int cnt = min(cursorA[b] - base, CAPB);

    if (t < 128) h[t] = 0;
    if (t >= 128 && t < 192) dh[t - 128] = 0;
    __syncthreads();
    for (int i = t; i < cnt; i += 512) {
        int p = pairs[base + i];
        buf[i] = p;
        atomicAdd(&h[p & BMASK], 1);
    }
    __syncthreads();

    // inclusive scan of h into sc: single wave, 2 bins/lane, shfl_up scan
    if (t < 64) {
        int a  = h[2 * t];
        int b2 = h[2 * t + 1];
        int s = a + b2;
        #pragma unroll
        for (int off = 1; off < 64; off <<= 1) {
            int x = __shfl_up(s, off);
            if (t >= off) s += x;
        }
        sc[2 * t]     = s - b2;   // inclusive through bin 2t
        sc[2 * t + 1] = s;        // inclusive through bin 2t+1
    }
    __syncthreads();
    if (t < 128) {
        cur[t] = sc[t] - h[t];                 // exclusive
        dv_s[t] = rsqrtf(fmaxf((float)h[t], 1.0f));
        atomicAdd(&dh[min(h[t], 63)], 1);      // degree histogram
    }
    __syncthreads();

    // exclusive scan of dh (64 bins, one wave), then rank-place nodes
    if (t < 64) {
        int v = dh[t];
        int s = v;
        #pragma unroll
        for (int off = 1; off < 64; off <<= 1) {
            int x = __shfl_up(s, off);
            if (t >= off) s += x;
        }
        dh[t] = s - v;                         // exclusive
    }
    __syncthreads();
    if (t < 128) {
        int pos = atomicAdd(&dh[min(h[t], 63)], 1);
        perm[pos] = t;
    }

    // scatter (runs concurrently with ranking; both complete at barrier)
    for (int i = t; i < cnt; i += 512) {
        int p = buf[i];
        int pos = atomicAdd(&cur[p & BMASK], 1);
        outb[pos] = p >> BSH;
    }
    __syncthreads();

    // gather: one (node, quad) per thread, degree-ranked node assignment
    const uint4* sf4 = reinterpret_cast<const uint4*>(sfeat);
    const v4f* featv = reinterpret_cast<const v4f*>(feat);
    v4f* outv = reinterpret_cast<v4f*>(out);

    {
        int nl = perm[t >> 2];                  // degree-ranked node
        int q = t & 3;
        int node = (b << BSH) + nl;
        if (node < N_NODES) {
            int en = sc[nl];
            int k = en - h[nl];
            float a0 = 0.f, a1 = 0.f, a2 = 0.f, a3 = 0.f;
            float a4 = 0.f, a5 = 0.f, a6 = 0.f, a7 = 0.f;

            #define ACC(r)                                                 \
                a0 += __uint_as_float((r).x << 16);                        \
                a1 += __uint_as_float((r).x & 0xFFFF0000u);                \
                a2 += __uint_as_float((r).y << 16);                        \
                a3 += __uint_as_float((r).y & 0xFFFF0000u);                \
                a4 += __uint_as_float((r).z << 16);                        \
                a5 += __uint_as_float((r).z & 0xFFFF0000u);                \
                a6 += __uint_as_float((r).w << 16);                        \
                a7 += __uint_as_float((r).w & 0xFFFF0000u);

            for (; k + 7 < en; k += 8) {
                int s0 = outb[k],     s1 = outb[k + 1];
                int s2 = outb[k + 2], s3 = outb[k + 3];
                int s4 = outb[k + 4], s5 = outb[k + 5];
                int s6 = outb[k + 6], s7 = outb[k + 7];
                uint4 r0 = sf4[s0 * 4 + q];
                uint4 r1 = sf4[s1 * 4 + q];
                uint4 r2 = sf4[s2 * 4 + q];
                uint4 r3 = sf4[s3 * 4 + q];
                uint4 r4 = sf4[s4 * 4 + q];
                uint4 r5 = sf4[s5 * 4 + q];
                uint4 r6 = sf4[s6 * 4 + q];
                uint4 r7 = sf4[s7 * 4 + q];
                ACC(r0) ACC(r1) ACC(r2) ACC(r3)
                ACC(r4) ACC(r5) ACC(r6) ACC(r7)
            }
            for (; k + 3 < en; k += 4) {
                int s0 = outb[k],     s1 = outb[k + 1];
                int s2 = outb[k + 2], s3 = outb[k + 3];
                uint4 r0 = sf4[s0 * 4 + q];
                uint4 r1 = sf4[s1 * 4 + q];
                uint4 r2 = sf4[s2 * 4 + q];
                uint4 r3 = sf4[s3 * 4 + q];
                ACC(r0) ACC(r1) ACC(r2) ACC(r3)
            }
            for (; k < en; ++k) {
                uint4 r = sf4[outb[k] * 4 + q];
                ACC(r)
            }
            #undef ACC

            float dvn = dv_s[nl];
            v4f fa = __builtin_nontemporal_load(&featv[node * 8 + 2 * q]);
            v4f fb = __builtin_nontemporal_load(&featv[node * 8 + 2 * q + 1]);
            v4f oa, ob;
            float y;
            y = 0.5f * (fa.x - a0 * dvn); oa.x = 2.0f * y * (fa.x - y);
            y = 0.5f * (fa.y - a1 * dvn); oa.y = 2.0f * y * (fa.y - y);
            y = 0.5f * (fa.z - a2 * dvn); oa.z = 2.0f * y * (fa.z - y);
            y = 0.5f * (fa.w - a3 * dvn); oa.w = 2.0f * y * (fa.w - y);
            y = 0.5f * (fb.x - a4 * dvn); ob.x = 2.0f * y * (fb.x - y);
            y = 0.5f * (fb.y - a5 * dvn); ob.y = 2.0f * y * (fb.y - y);
            y = 0.5f * (fb.z - a6 * dvn); ob.z = 2.0f * y * (fb.z - y);
            y = 0.5f * (fb.w - a7 * dvn); ob.w = 2.0f * y * (fb.w - y);
            __builtin_nontemporal_store(oa, &outv[node * 8 + 2 * q]);
            __builtin_nontemporal_store(ob, &outv[node * 8 + 2 * q + 1]);
        }
    }
}

extern "C" void kernel_launch(void* const* d_in, const int* in_sizes, int n_in,
                              void* d_out, int out_size, void* d_ws, size_t ws_size,
                              hipStream_t stream) {
    const float* feat = (const float*)d_in[0];
    const int* edge_src = (const int*)d_in[1];
    const int* edge_dst = (const int*)d_in[2];
    float* out = (float*)d_out;

    int* ws = (int*)d_ws;
    int* cursorA    = ws;                              // 1024
    int* pairs      = cursorA + 1024;                  // NB*CAPB
    unsigned* sfeat = (unsigned*)(pairs + NB * CAPB);  // N_NODES*16

    init_kernel<<<1, 1024, 0, stream>>>(cursorA);
    {
        int blocks = (N_EDGES + P1_TILE - 1) / P1_TILE;   // 391
        bucket_kernel<<<blocks, P1_BS, 0, stream>>>(edge_src, edge_dst,
                                                    cursorA, pairs, N_EDGES);
    }
    prep_kernel<<<NB, 512, 0, stream>>>(pairs, cursorA, feat, sfeat);
    sortgather_kernel<<<NB, 512, 0, stream>>>(pairs, cursorA, feat, sfeat, out);
}

// Round 13
// 113.323 us; speedup vs baseline: 1.0116x; 1.0116x over previous
//
#include <hip/hip_runtime.h>

#define N_NODES 100000
#define N_EDGES 1600000
#define D_FEAT 32

#define BSH 7                 // bucket = dst >> 7  (128 nodes per bucket)
#define BMASK 127
#define NB 782                // ceil(100000/128)
#define CAPB 2432             // per-bucket capacity (mean 2046, ~8.5 sigma pad)

#define P1_BS 1024            // 4 edges/thread (1 int4 pair)
#define P1_TILE 4096
#define P1_CAP 16             // staging per bucket per block (mean ~5.2)

// ws layout (4-byte words):
//   cursorA [1024]        int    per-bucket fill cursors (init to b*CAPB)
//   pairs   [NB*CAPB]     int    packed (src<<7)|(dst&127), bucket-grouped
//   sfeat   [N_NODES*16]  uint   bf16-packed feat*dinv (2 feats per uint)
//
// FINAL (R13): empirically best configuration (R6, 112.96 us), restored
// verbatim after R7-R12 structural experiments all measured null or
// negative. Falsified theories for the remaining ~63 us of kernel+gap
// time (fixed ~46 us harness poison-fill excluded):
//   - per-block fixed cost in bucket (R6/R9 tile-size: null)
//   - cursor atomic contention (R7 deterministic placement: -15 us, traffic wins)
//   - duplicated per-edge DS work (R11 dedup: null)
//   - gather wave divergence (R12 degree-ranked: null)
//   - edge-parallel LDS f32 atomics (R3/R5: compiler lowers to non-DS
//     path, 340 us, SQ_LDS_BANK_CONFLICT==0 signature)
//   - scattered global atomics (R5: ~34ns each, +55 us)
//   - single cooperative kernel (R8: silent launch failure at 391 blocks)
// Dispatch count (init + bucket -> prep -> sortgather) is at the legal
// minimum given deg/dinv and cross-bucket sfeat dependencies.

typedef float v4f __attribute__((ext_vector_type(4)));   // native vec for nontemporal builtins

static __device__ __forceinline__ unsigned pack_bf16(float a, float b) {
    unsigned ua = __float_as_uint(a);
    unsigned ub = __float_as_uint(b);
    ua = (ua + 0x7FFFu + ((ua >> 16) & 1u)) >> 16;   // RNE
    ub = (ub + 0x7FFFu + ((ub >> 16) & 1u)) >> 16;
    return (ua & 0xFFFFu) | (ub << 16);
}

__global__ void init_kernel(int* __restrict__ cursorA) {
    int b = blockIdx.x * blockDim.x + threadIdx.x;
    if (b < NB) cursorA[b] = b * CAPB;
}

// Pass 1: bucket edges by dst>>7 with LDS staging -> coalesced runs into
// fixed per-bucket regions. 1024 threads, 4 edges/thread. Slot-parallel drain.
__global__ void __launch_bounds__(P1_BS)
bucket_kernel(const int* __restrict__ edge_src,
              const int* __restrict__ edge_dst,
              int* __restrict__ cursorA,
              int* __restrict__ pairs, int n_edges) {
    __shared__ int s_cnt[NB];
    __shared__ int s_base[NB];
    __shared__ int s_buf[NB * P1_CAP];   // 782*16*4 = 50 KB

    int tile = blockIdx.x * P1_TILE;
    if (tile >= n_edges) return;

    for (int b = threadIdx.x; b < NB; b += P1_BS) s_cnt[b] = 0;
    __syncthreads();

    const int4* src4 = reinterpret_cast<const int4*>(edge_src);
    const int4* dst4 = reinterpret_cast<const int4*>(edge_dst);
    int tileq = blockIdx.x * (P1_TILE / 4);
    {
        int iq = tileq + threadIdx.x;            // 1024 int4s == 4096 edges
        if (iq * 4 < n_edges) {
            int4 sv = src4[iq];
            int4 dv = dst4[iq];
            int ss[4] = {sv.x, sv.y, sv.z, sv.w};
            int dd[4] = {dv.x, dv.y, dv.z, dv.w};
            #pragma unroll
            for (int u = 0; u < 4; ++u) {
                int b = dd[u] >> BSH;
                int packed = (ss[u] << BSH) | (dd[u] & BMASK);
                int p = atomicAdd(&s_cnt[b], 1);
                if (p < P1_CAP) {
                    s_buf[b * P1_CAP + p] = packed;
                } else {
                    int gp = atomicAdd(&cursorA[b], 1);   // rare overflow
                    pairs[gp] = packed;
                }
            }
        }
    }
    __syncthreads();

    for (int b = threadIdx.x; b < NB; b += P1_BS) {
        int c = min(s_cnt[b], P1_CAP);
        s_cnt[b] = c;
        s_base[b] = atomicAdd(&cursorA[b], c);
    }
    __syncthreads();

    // slot-parallel drain: 12512 slots / 1024 threads = 13 rounds
    for (int idx = threadIdx.x; idx < NB * P1_CAP; idx += P1_BS) {
        int b = idx >> 4;                 // P1_CAP == 16
        int slot = idx & (P1_CAP - 1);
        if (slot < s_cnt[b])
            pairs[s_base[b] + slot] = s_buf[idx];
    }
}

// Pass 2: one WG per bucket — degree histogram + bf16 sfeat rows.
__global__ void __launch_bounds__(512)
prep_kernel(const int* __restrict__ pairs,
            const int* __restrict__ cursorA,
            const float* __restrict__ feat,
            unsigned* __restrict__ sfeat) {
    __shared__ int h[128];
    __shared__ float dv_s[128];

    int b = blockIdx.x;
    int t = threadIdx.x;
    int base = b * CAPB;
    int cnt = min(cursorA[b] - base, CAPB);

    if (t < 128) h[t] = 0;
    __syncthreads();
    for (int i = t; i < cnt; i += 512)
        atomicAdd(&h[pairs[base + i] & BMASK], 1);
    __syncthreads();

    if (t < 128)
        dv_s[t] = rsqrtf(fmaxf((float)h[t], 1.0f));
    __syncthreads();

    // bf16 sfeat rows: sfeat[n] = bf16(feat[n] * dinv[n]), uint4 per 8 feats
    const float4* feat4 = reinterpret_cast<const float4*>(feat);
    uint4* sf4 = reinterpret_cast<uint4*>(sfeat);
    for (int idx = t; idx < 128 * 4; idx += 512) {
        int nl = idx >> 2;
        int q = idx & 3;
        int node = (b << BSH) + nl;
        if (node >= N_NODES) continue;
        float dvv = dv_s[nl];
        float4 fa = feat4[node * 8 + 2 * q];
        float4 fb = feat4[node * 8 + 2 * q + 1];
        uint4 pk;
        pk.x = pack_bf16(fa.x * dvv, fa.y * dvv);
        pk.y = pack_bf16(fa.z * dvv, fa.w * dvv);
        pk.z = pack_bf16(fb.x * dvv, fb.y * dvv);
        pk.w = pack_bf16(fb.z * dvv, fb.w * dvv);
        sf4[node * 4 + q] = pk;
    }
}

// Pass 3: one WG (512 threads) per bucket — fused counting sort (LDS only)
// + gather + Bernstein epilogue. Gather is one (node, quad) per thread.
__global__ void __launch_bounds__(512)
sortgather_kernel(const int* __restrict__ pairs,
                  const int* __restrict__ cursorA,
                  const float* __restrict__ feat,
                  const unsigned* __restrict__ sfeat,
                  float* __restrict__ out) {
    __shared__ int buf[CAPB];     // 9.5 KB
    __shared__ int outb[CAPB];    // 9.5 KB  (dst-sorted srcs)
    __shared__ int h[128];
    __shared__ int sc[128];
    __shared__ int cur[128];
    __shared__ float dv_s[128];

    int b = blockIdx.x;
    int t = threadIdx.x;
    int base = b * CAPB;
    int cnt = min(cursorA[b] - base, CAPB);

    if (t < 128) h[t] = 0;
    __syncthreads();
    for (int i = t; i < cnt; i += 512) {
        int p = pairs[base + i];
        buf[i] = p;
        atomicAdd(&h[p & BMASK], 1);
    }
    __syncthreads();

    // inclusive scan of h into sc: single wave, 2 bins/lane, shfl_up scan
    if (t < 64) {
        int a  = h[2 * t];
        int b2 = h[2 * t + 1];
        int s = a + b2;
        #pragma unroll
        for (int off = 1; off < 64; off <<= 1) {
            int x = __shfl_up(s, off);
            if (t >= off) s += x;
        }
        sc[2 * t]     = s - b2;   // inclusive through bin 2t
        sc[2 * t + 1] = s;        // inclusive through bin 2t+1
    }
    __syncthreads();
    if (t < 128) {
        cur[t] = sc[t] - h[t];                 // exclusive
        dv_s[t] = rsqrtf(fmaxf((float)h[t], 1.0f));
    }
    __syncthreads();

    for (int i = t; i < cnt; i += 512) {
        int p = buf[i];
        int pos = atomicAdd(&cur[p & BMASK], 1);
        outb[pos] = p >> BSH;
    }
    __syncthreads();

    // gather: one (node, quad) per thread; srcs from LDS outb
    const uint4* sf4 = reinterpret_cast<const uint4*>(sfeat);
    const v4f* featv = reinterpret_cast<const v4f*>(feat);
    v4f* outv = reinterpret_cast<v4f*>(out);

    {
        int nl = t >> 2;                        // 0..127
        int q = t & 3;
        int node = (b << BSH) + nl;
        if (node < N_NODES) {
            int en = sc[nl];
            int k = en - h[nl];
            float a0 = 0.f, a1 = 0.f, a2 = 0.f, a3 = 0.f;
            float a4 = 0.f, a5 = 0.f, a6 = 0.f, a7 = 0.f;

            #define ACC(r)                                                 \
                a0 += __uint_as_float((r).x << 16);                        \
                a1 += __uint_as_float((r).x & 0xFFFF0000u);                \
                a2 += __uint_as_float((r).y << 16);                        \
                a3 += __uint_as_float((r).y & 0xFFFF0000u);                \
                a4 += __uint_as_float((r).z << 16);                        \
                a5 += __uint_as_float((r).z & 0xFFFF0000u);                \
                a6 += __uint_as_float((r).w << 16);                        \
                a7 += __uint_as_float((r).w & 0xFFFF0000u);

            for (; k + 7 < en; k += 8) {
                int s0 = outb[k],     s1 = outb[k + 1];
                int s2 = outb[k + 2], s3 = outb[k + 3];
                int s4 = outb[k + 4], s5 = outb[k + 5];
                int s6 = outb[k + 6], s7 = outb[k + 7];
                uint4 r0 = sf4[s0 * 4 + q];
                uint4 r1 = sf4[s1 * 4 + q];
                uint4 r2 = sf4[s2 * 4 + q];
                uint4 r3 = sf4[s3 * 4 + q];
                uint4 r4 = sf4[s4 * 4 + q];
                uint4 r5 = sf4[s5 * 4 + q];
                uint4 r6 = sf4[s6 * 4 + q];
                uint4 r7 = sf4[s7 * 4 + q];
                ACC(r0) ACC(r1) ACC(r2) ACC(r3)
                ACC(r4) ACC(r5) ACC(r6) ACC(r7)
            }
            for (; k + 3 < en; k += 4) {
                int s0 = outb[k],     s1 = outb[k + 1];
                int s2 = outb[k + 2], s3 = outb[k + 3];
                uint4 r0 = sf4[s0 * 4 + q];
                uint4 r1 = sf4[s1 * 4 + q];
                uint4 r2 = sf4[s2 * 4 + q];
                uint4 r3 = sf4[s3 * 4 + q];
                ACC(r0) ACC(r1) ACC(r2) ACC(r3)
            }
            for (; k < en; ++k) {
                uint4 r = sf4[outb[k] * 4 + q];
                ACC(r)
            }
            #undef ACC

            float dvn = dv_s[nl];
            v4f fa = __builtin_nontemporal_load(&featv[node * 8 + 2 * q]);
            v4f fb = __builtin_nontemporal_load(&featv[node * 8 + 2 * q + 1]);
            v4f oa, ob;
            float y;
            y = 0.5f * (fa.x - a0 * dvn); oa.x = 2.0f * y * (fa.x - y);
            y = 0.5f * (fa.y - a1 * dvn); oa.y = 2.0f * y * (fa.y - y);
            y = 0.5f * (fa.z - a2 * dvn); oa.z = 2.0f * y * (fa.z - y);
            y = 0.5f * (fa.w - a3 * dvn); oa.w = 2.0f * y * (fa.w - y);
            y = 0.5f * (fb.x - a4 * dvn); ob.x = 2.0f * y * (fb.x - y);
            y = 0.5f * (fb.y - a5 * dvn); ob.y = 2.0f * y * (fb.y - y);
            y = 0.5f * (fb.z - a6 * dvn); ob.z = 2.0f * y * (fb.z - y);
            y = 0.5f * (fb.w - a7 * dvn); ob.w = 2.0f * y * (fb.w - y);
            __builtin_nontemporal_store(oa, &outv[node * 8 + 2 * q]);
            __builtin_nontemporal_store(ob, &outv[node * 8 + 2 * q + 1]);
        }
    }
}

extern "C" void kernel_launch(void* const* d_in, const int* in_sizes, int n_in,
                              void* d_out, int out_size, void* d_ws, size_t ws_size,
                              hipStream_t stream) {
    const float* feat = (const float*)d_in[0];
    const int* edge_src = (const int*)d_in[1];
    const int* edge_dst = (const int*)d_in[2];
    float* out = (float*)d_out;

    int* ws = (int*)d_ws;
    int* cursorA    = ws;                              // 1024
    int* pairs      = cursorA + 1024;                  // NB*CAPB
    unsigned* sfeat = (unsigned*)(pairs + NB * CAPB);  // N_NODES*16

    init_kernel<<<1, 1024, 0, stream>>>(cursorA);
    {
        int blocks = (N_EDGES + P1_TILE - 1) / P1_TILE;   // 391
        bucket_kernel<<<blocks, P1_BS, 0, stream>>>(edge_src, edge_dst,
                                                    cursorA, pairs, N_EDGES);
    }
    prep_kernel<<<NB, 512, 0, stream>>>(pairs, cursorA, feat, sfeat);
    sortgather_kernel<<<NB, 512, 0, stream>>>(pairs, cursorA, feat, sfeat, out);
}